// Round 3
// baseline (233.906 us; speedup 1.0000x reference)
//
#include <hip/hip_runtime.h>
#include <math.h>

#define B 32
#define K 4
#define C 256
#define HW 1024          // H*W = 32*32
#define NT 5             // K+1 tensors (y, x0..x3)
#define MID 32
#define FEAT 1280        // NT*C
#define EPS 1e-5f

// ---------------------------------------------------------------------------
// Kernel 1: spatial means.  One wave reduces FOUR consecutive c-slices
// (4 x 4 KiB = 16 KiB contiguous): 16 independent coalesced float4 loads per
// lane in flight (256 B/lane), then one 4-value butterfly reduce and a single
// float4 store.  Grid: NT*B*C/4 waves / 4 waves per block.
// feats layout: [B][FEAT], slot t*C+c (t=0 is y, t=1..4 are x0..x3).
// ---------------------------------------------------------------------------
__global__ __launch_bounds__(256) void mean_kernel(
    const float* __restrict__ y,
    const float* __restrict__ x0, const float* __restrict__ x1,
    const float* __restrict__ x2, const float* __restrict__ x3,
    float* __restrict__ feats)
{
    const int wave = (blockIdx.x << 2) + (threadIdx.x >> 6);  // 0..10239
    const int lane = threadIdx.x & 63;
    const int t    = wave >> 11;          // / 2048  (B*C/4 groups per tensor)
    const int rem  = wave & 2047;
    const int b    = rem >> 6;            // 64 c-groups per b
    const int g    = rem & 63;            // c0 = g*4
    const float* src = (t == 0) ? y : (t == 1) ? x0 : (t == 2) ? x1
                                    : (t == 3) ? x2 : x3;
    const float4* p = (const float4*)(src + ((size_t)(b * C) + g * 4) * HW);

    float4 v[4][4];
#pragma unroll
    for (int s = 0; s < 4; ++s)
#pragma unroll
        for (int j = 0; j < 4; ++j)
            v[s][j] = p[s * 256 + j * 64 + lane];

    float s0 = 0.f, s1 = 0.f, s2 = 0.f, s3 = 0.f;
#pragma unroll
    for (int j = 0; j < 4; ++j) {
        s0 += v[0][j].x + v[0][j].y + v[0][j].z + v[0][j].w;
        s1 += v[1][j].x + v[1][j].y + v[1][j].z + v[1][j].w;
        s2 += v[2][j].x + v[2][j].y + v[2][j].z + v[2][j].w;
        s3 += v[3][j].x + v[3][j].y + v[3][j].z + v[3][j].w;
    }
#pragma unroll
    for (int m = 32; m >= 1; m >>= 1) {
        s0 += __shfl_xor(s0, m);
        s1 += __shfl_xor(s1, m);
        s2 += __shfl_xor(s2, m);
        s3 += __shfl_xor(s3, m);
    }
    if (lane == 0) {
        float4 r = make_float4(s0, s1, s2, s3);
        r.x *= (1.0f / 1024.0f); r.y *= (1.0f / 1024.0f);
        r.z *= (1.0f / 1024.0f); r.w *= (1.0f / 1024.0f);
        *((float4*)&feats[b * FEAT + t * C + g * 4]) = r;
    }
}

// ---------------------------------------------------------------------------
// Kernel 2: gate MLP.  One block (512 threads = 8 waves) per batch element.
// GEMM1 is read coalesced: wave w owns rows m = 4w..4w+3 of conv1_w; each
// lane reads 5 float4 per row (contiguous 1280 floats), dot with feats_s,
// 4-value butterfly reduce, lane0 applies BN+ReLU.
// GEMM2: threads 0..255 (c = tid) compute all 5 output slots in registers.
// ---------------------------------------------------------------------------
__global__ __launch_bounds__(512) void gate_kernel(
    const float* __restrict__ feats,
    const float* __restrict__ conv1_w,   // [MID][FEAT]
    const float* __restrict__ bn_gamma, const float* __restrict__ bn_beta,
    const float* __restrict__ bn_mean,  const float* __restrict__ bn_var,
    const float* __restrict__ conv2_w,   // [FEAT][MID]
    const float* __restrict__ conv2_b,   // [FEAT]
    float* __restrict__ gates)           // [B][NT][C]
{
    __shared__ __align__(16) float feats_s[FEAT];
    __shared__ float h_s[MID];

    const int b    = blockIdx.x;
    const int tid  = threadIdx.x;
    const int wave = tid >> 6;
    const int lane = tid & 63;

    for (int i = tid; i < FEAT; i += 512) feats_s[i] = feats[b * FEAT + i];
    __syncthreads();

    // ---- GEMM1 (coalesced): rows m = wave*4 .. wave*4+3 ----
    const float4* fs = (const float4*)feats_s;
    float4 wv[4][5];
#pragma unroll
    for (int r = 0; r < 4; ++r) {
        const float4* wp = (const float4*)(conv1_w + (wave * 4 + r) * FEAT);
#pragma unroll
        for (int k = 0; k < 5; ++k) wv[r][k] = wp[lane + 64 * k];
    }
    float a0 = 0.f, a1 = 0.f, a2 = 0.f, a3 = 0.f;
#pragma unroll
    for (int k = 0; k < 5; ++k) {
        float4 f = fs[lane + 64 * k];
        a0 += wv[0][k].x * f.x + wv[0][k].y * f.y + wv[0][k].z * f.z + wv[0][k].w * f.w;
        a1 += wv[1][k].x * f.x + wv[1][k].y * f.y + wv[1][k].z * f.z + wv[1][k].w * f.w;
        a2 += wv[2][k].x * f.x + wv[2][k].y * f.y + wv[2][k].z * f.z + wv[2][k].w * f.w;
        a3 += wv[3][k].x * f.x + wv[3][k].y * f.y + wv[3][k].z * f.z + wv[3][k].w * f.w;
    }
#pragma unroll
    for (int m = 32; m >= 1; m >>= 1) {
        a0 += __shfl_xor(a0, m);
        a1 += __shfl_xor(a1, m);
        a2 += __shfl_xor(a2, m);
        a3 += __shfl_xor(a3, m);
    }
    if (lane == 0) {
        float acc[4] = {a0, a1, a2, a3};
#pragma unroll
        for (int r = 0; r < 4; ++r) {
            const int m = wave * 4 + r;
            float inv = rsqrtf(bn_var[m] + EPS);
            float hv  = (acc[r] - bn_mean[m]) * (bn_gamma[m] * inv) + bn_beta[m];
            h_s[m] = fmaxf(hv, 0.f);
        }
    }
    __syncthreads();

    // ---- GEMM2 + nonlinearities: thread tid (<256) == channel c ----
    if (tid < 256) {
        float wvout[5];
#pragma unroll
        for (int r = 0; r < 5; ++r) {
            const int j = r * 256 + tid;
            const float4* w2 = (const float4*)(conv2_w + j * MID);
            float a = conv2_b[j];
#pragma unroll
            for (int i = 0; i < 8; ++i) {
                float4 q = w2[i];
                a += q.x * h_s[i * 4]     + q.y * h_s[i * 4 + 1]
                   + q.z * h_s[i * 4 + 2] + q.w * h_s[i * 4 + 3];
            }
            wvout[r] = a;
        }
        const float w1 = 1.f / (1.f + expf(-wvout[0]));
        const float mx = fmaxf(fmaxf(wvout[1], wvout[2]), fmaxf(wvout[3], wvout[4]));
        const float e1 = expf(wvout[1] - mx), e2 = expf(wvout[2] - mx);
        const float e3 = expf(wvout[3] - mx), e4 = expf(wvout[4] - mx);
        const float inv = 1.f / (e1 + e2 + e3 + e4);
        gates[b * FEAT +        tid] = w1;
        gates[b * FEAT +  256 + tid] = e1 * inv;
        gates[b * FEAT +  512 + tid] = e2 * inv;
        gates[b * FEAT +  768 + tid] = e3 * inv;
        gates[b * FEAT + 1024 + tid] = e4 * inv;
    }
}

// ---------------------------------------------------------------------------
// Kernel 3: out[b,c,:,:] = g0*y + g1*x0 + g2*x1 + g3*x2 + g4*x3.
// One block per TWO (b,c) slices: each 128-thread half owns one slice;
// 10 independent float4 loads + 2 stores per thread (160 B/lane in flight).
// Gate scalars stay wave-uniform.
// ---------------------------------------------------------------------------
__global__ __launch_bounds__(256) void out_kernel(
    const float* __restrict__ y,
    const float* __restrict__ x0, const float* __restrict__ x1,
    const float* __restrict__ x2, const float* __restrict__ x3,
    const float* __restrict__ gates,
    float* __restrict__ out)
{
    const int half  = threadIdx.x >> 7;           // 0/1
    const int idx   = threadIdx.x & 127;
    const int slice = blockIdx.x * 2 + half;      // b*C + c, 0..8191
    const int b     = slice >> 8;
    const int c     = slice & 255;

    const float g0 = gates[b * FEAT +        c];
    const float g1 = gates[b * FEAT +  256 + c];
    const float g2 = gates[b * FEAT +  512 + c];
    const float g3 = gates[b * FEAT +  768 + c];
    const float g4 = gates[b * FEAT + 1024 + c];

    const size_t base = (size_t)slice * HW;
    const float4* py = (const float4*)(y  + base);
    const float4* p0 = (const float4*)(x0 + base);
    const float4* p1 = (const float4*)(x1 + base);
    const float4* p2 = (const float4*)(x2 + base);
    const float4* p3 = (const float4*)(x3 + base);

    float4 ya = py[idx], yb = py[idx + 128];
    float4 aa = p0[idx], ab = p0[idx + 128];
    float4 ba = p1[idx], bb = p1[idx + 128];
    float4 ca = p2[idx], cb = p2[idx + 128];
    float4 da = p3[idx], db = p3[idx + 128];

    float4 r0, r1;
    r0.x = ya.x * g0 + aa.x * g1 + ba.x * g2 + ca.x * g3 + da.x * g4;
    r0.y = ya.y * g0 + aa.y * g1 + ba.y * g2 + ca.y * g3 + da.y * g4;
    r0.z = ya.z * g0 + aa.z * g1 + ba.z * g2 + ca.z * g3 + da.z * g4;
    r0.w = ya.w * g0 + aa.w * g1 + ba.w * g2 + ca.w * g3 + da.w * g4;
    r1.x = yb.x * g0 + ab.x * g1 + bb.x * g2 + cb.x * g3 + db.x * g4;
    r1.y = yb.y * g0 + ab.y * g1 + bb.y * g2 + cb.y * g3 + db.y * g4;
    r1.z = yb.z * g0 + ab.z * g1 + bb.z * g2 + cb.z * g3 + db.z * g4;
    r1.w = yb.w * g0 + ab.w * g1 + bb.w * g2 + cb.w * g3 + db.w * g4;

    float4* po = (float4*)(out + base);
    po[idx]       = r0;
    po[idx + 128] = r1;
}

// ---------------------------------------------------------------------------
extern "C" void kernel_launch(void* const* d_in, const int* in_sizes, int n_in,
                              void* d_out, int out_size, void* d_ws, size_t ws_size,
                              hipStream_t stream) {
    const float* y        = (const float*)d_in[0];
    const float* x0       = (const float*)d_in[1];
    const float* x1       = (const float*)d_in[2];
    const float* x2       = (const float*)d_in[3];
    const float* x3       = (const float*)d_in[4];
    const float* conv1_w  = (const float*)d_in[5];
    const float* bn_gamma = (const float*)d_in[6];
    const float* bn_beta  = (const float*)d_in[7];
    const float* bn_mean  = (const float*)d_in[8];
    const float* bn_var   = (const float*)d_in[9];
    const float* conv2_w  = (const float*)d_in[10];
    const float* conv2_b  = (const float*)d_in[11];

    float* feats = (float*)d_ws;             // [B][FEAT]
    float* gates = feats + B * FEAT;         // [B][NT][C]
    float* out   = (float*)d_out;

    // 1) means: NT*B*C/4 = 10240 slice-groups -> 1 wave each, 4 waves/block
    mean_kernel<<<(NT * B * C / 4) / 4, 256, 0, stream>>>(y, x0, x1, x2, x3, feats);
    // 2) gate MLP: one block per batch element
    gate_kernel<<<B, 512, 0, stream>>>(feats, conv1_w, bn_gamma, bn_beta,
                                       bn_mean, bn_var, conv2_w, conv2_b, gates);
    // 3) gated sum: one block per two (b,c) slices
    out_kernel<<<B * C / 2, 256, 0, stream>>>(y, x0, x1, x2, x3, gates, out);
}